// Round 11
// baseline (132.765 us; speedup 1.0000x reference)
//
#include <hip/hip_runtime.h>

typedef unsigned short u16;
typedef __bf16 bf16x8 __attribute__((ext_vector_type(8)));
typedef float    f32x4 __attribute__((ext_vector_type(4)));
typedef float   f32x16 __attribute__((ext_vector_type(16)));
typedef u16      u16x8 __attribute__((ext_vector_type(8)));
typedef u16      u16x4 __attribute__((ext_vector_type(4)));
typedef unsigned uint4v __attribute__((ext_vector_type(4)));

#define DM 1024
#define SQ 2048
#define HD 64
#define QSCALE 0.18033688f   /* (1/sqrt(64)) * log2(e), folded into Wq/bq */

// attn LDS bank swizzle (64-col rows, 32-row read groups) — 0-conflict (R4+)
#define SWZ8(row, ch) ((((ch) ^ ((row) & 7) ^ ((row) >> 3)) & 7))

__device__ __forceinline__ u16 f2bf(float f) {
    unsigned u = __builtin_bit_cast(unsigned, f);
    u += 0x7FFFu + ((u >> 16) & 1u);   // RTNE
    return (u16)(u >> 16);
}

__device__ __forceinline__ bf16x8 ldsbf(const u16* p) {
    return __builtin_bit_cast(bf16x8, *(const u16x8*)p);
}

__device__ __forceinline__ unsigned cvtpk(float a, float b) {
    unsigned r;
    asm("v_cvt_pk_bf16_f32 %0, %1, %2" : "=v"(r) : "v"(a), "v"(b));
    return r;
}

__device__ __forceinline__ void swap32(unsigned &a, unsigned &b) {
    asm volatile("v_permlane32_swap_b32 %0, %1" : "+v"(a), "+v"(b));
}

typedef __attribute__((address_space(3))) unsigned lds_u32_t;
typedef __attribute__((address_space(1))) const unsigned glob_u32_t;
__device__ __forceinline__ void gl_lds16(const u16* g, u16* l) {
    __builtin_amdgcn_global_load_lds((glob_u32_t*)g, (lds_u32_t*)l, 16, 0, 0);
}

// ---------------------------------------------------------------------------
// fp32 -> bf16 bulk convert for q,k,v activations (4096x1024 each)
// ---------------------------------------------------------------------------
__global__ __launch_bounds__(256) void convert_kernel(
    const float* __restrict__ q, const float* __restrict__ k,
    const float* __restrict__ v,
    u16* __restrict__ Qc, u16* __restrict__ Kc, u16* __restrict__ Vc)
{
    const int which = blockIdx.x >> 11;            // 2048 blocks per tensor
    const float* src = (which==0) ? q : (which==1) ? k : v;
    u16* dst         = (which==0) ? Qc : (which==1) ? Kc : Vc;
    const int off = ((blockIdx.x & 2047) << 11) + threadIdx.x * 8;
    f32x4 x0 = *(const f32x4*)&src[off];
    f32x4 x1 = *(const f32x4*)&src[off + 4];
    u16x8 u;
#pragma unroll
    for (int e = 0; e < 4; ++e) { u[e] = f2bf(x0[e]); u[e+4] = f2bf(x1[e]); }
    *(u16x8*)&dst[off] = u;
}

// ---------------------------------------------------------------------------
// Weight transpose + fp32->bf16 convert:  W[k][n] (f32) -> Wt[n][k] (bf16)
// z==0 (Wq) is pre-scaled by QSCALE (score scale folded into Q projection)
// ---------------------------------------------------------------------------
__global__ __launch_bounds__(256) void wtrans_kernel(
    const float* __restrict__ w0, const float* __restrict__ w1,
    const float* __restrict__ w2, const float* __restrict__ w3,
    u16* __restrict__ t0, u16* __restrict__ t1,
    u16* __restrict__ t2, u16* __restrict__ t3)
{
    __shared__ float tile[32][33];
    const int z = blockIdx.z;
    const float* W = (z==0) ? w0 : (z==1) ? w1 : (z==2) ? w2 : w3;
    u16* T        = (z==0) ? t0 : (z==1) ? t1 : (z==2) ? t2 : t3;
    const float sc = (z==0) ? QSCALE : 1.0f;
    const int tx = threadIdx.x & 31, ty = threadIdx.x >> 5;
    const int n0 = blockIdx.x * 32, k0 = blockIdx.y * 32;
#pragma unroll
    for (int i = 0; i < 4; ++i)
        tile[ty + 8*i][tx] = W[(size_t)(k0 + ty + 8*i)*DM + n0 + tx];
    __syncthreads();
#pragma unroll
    for (int i = 0; i < 4; ++i)
        T[(size_t)(n0 + ty + 8*i)*DM + k0 + tx] = f2bf(tile[tx][ty + 8*i] * sc);
}

// ---------------------------------------------------------------------------
// GEMM  C[4096][1024] = A[4096][1024](bf16) @ W + bias,  W as Wt[n][k] bf16.
// 128x128 tile, BK=64, THREE-buffer depth-2 counted-vmcnt pipeline (96 KB):
//   stage(t+2) -> vmcnt(16) (8 gl_lds/stage; never 0 until tail) -> barrier
//   -> 16 ds_read + 32 MFMA -> barrier.  Prefetch slack = 2 steps (~1600cyc)
//   > HBM latency (~900cyc).  16 K-steps only.
// Staging via global_load_lds w=16, pre-swizzled source ch^(row&7) (R3: 0-cf).
// XCD-chunked 1-D grid.  bscale0 applied to bias when z==0 (QSCALE folding).
// VTLAST: z==2 output stored transposed per head: Vt[(b*16+h)*64+d][s]
// ---------------------------------------------------------------------------
template<bool OF32, bool VTLAST>
__global__ __launch_bounds__(256) void gemm_kernel(
    const u16* __restrict__ a0, const u16* __restrict__ a1, const u16* __restrict__ a2,
    const u16* __restrict__ w0, const u16* __restrict__ w1, const u16* __restrict__ w2,
    const float* __restrict__ bi0, const float* __restrict__ bi1, const float* __restrict__ bi2,
    void* __restrict__ o0, void* __restrict__ o1, void* __restrict__ o2,
    float bscale0)
{
    __shared__ __align__(16) u16 As[3][128*64];
    __shared__ __align__(16) u16 Bs[3][128*64];

    const int cpx  = gridDim.x >> 3;
    const int wgid = (blockIdx.x & 7) * cpx + (blockIdx.x >> 3);
    const int z   = wgid >> 8;
    const int rem = wgid & 255;
    const int by  = rem >> 3, bx = rem & 7;

    const u16*  Ap  = (z==0) ? a0 : (z==1) ? a1 : a2;
    const u16*  Wp  = (z==0) ? w0 : (z==1) ? w1 : w2;
    const float* Bp = (z==0) ? bi0 : (z==1) ? bi1 : bi2;
    void* Op        = (z==0) ? o0 : (z==1) ? o1 : o2;
    const float bsc = (z==0) ? bscale0 : 1.0f;

    const int tid  = threadIdx.x;
    const int lane = tid & 63;
    const int wv   = tid >> 6;
    const int m0 = by * 128;
    const int n0 = bx * 128;
    const int wr = (wv >> 1) * 64;
    const int wc = (wv & 1) * 64;
    const int g  = lane >> 4;
    const int mm = lane & 15;

    const int l8 = lane >> 3;                 // 0..7: row within 8-row stripe
    const int c8 = lane & 7;                  // chunk lane

    f32x4 acc[4][4];
#pragma unroll
    for (int i = 0; i < 4; ++i)
#pragma unroll
        for (int j = 0; j < 4; ++j) acc[i][j] = f32x4{0.f,0.f,0.f,0.f};

    // stage a 128x64 tile: 4 issues x (4 waves x 8 rows), 8 gl_lds/wave total
    auto stageA = [&](int kt, int buf) {
#pragma unroll
        for (int i = 0; i < 4; ++i) {
            const int row = i*32 + wv*8 + l8;
            const int ch  = c8 ^ (row & 7);   // pre-swizzled source chunk
            gl_lds16(&Ap[(size_t)(m0+row)*DM + kt*64 + ch*8],
                     &As[buf][(i*32 + wv*8)*64]);
        }
    };
    auto stageW = [&](int kt, int buf) {
#pragma unroll
        for (int i = 0; i < 4; ++i) {
            const int row = i*32 + wv*8 + l8;
            const int ch  = c8 ^ (row & 7);
            gl_lds16(&Wp[(size_t)(n0+row)*DM + kt*64 + ch*8],
                     &Bs[buf][(i*32 + wv*8)*64]);
        }
    };

    // prologue: tiles 0 and 1 in flight (16 gl_lds/wave outstanding)
    stageA(0, 0); stageW(0, 0);
    stageA(1, 1); stageW(1, 1);

    int cur = 0;
    for (int kt = 0; kt < 16; ++kt) {
        const int nx2 = (cur >= 1) ? cur - 1 : 2;     // (kt+2) % 3
        if (kt < 14) { stageA(kt + 2, nx2); stageW(kt + 2, nx2); }
        // wait for stage(kt) only (8 instr); kt+1/kt+2 (8 each) stay in flight
        if (kt < 14)      asm volatile("s_waitcnt vmcnt(16)" ::: "memory");
        else if (kt < 15) asm volatile("s_waitcnt vmcnt(8)"  ::: "memory");
        else              asm volatile("s_waitcnt vmcnt(0)"  ::: "memory");
        __builtin_amdgcn_s_barrier();                 // stage(kt) visible
        __builtin_amdgcn_sched_barrier(0);

#pragma unroll
        for (int ks = 0; ks < 2; ++ks) {
            bf16x8 af[4], bfr[4];
#pragma unroll
            for (int rt = 0; rt < 4; ++rt) {
                const int row = wr + rt*16 + mm;
                const int ch  = ks*4 + g;
                af[rt] = ldsbf(&As[cur][row*64 + ((ch ^ (row & 7)) << 3)]);
            }
#pragma unroll
            for (int ct = 0; ct < 4; ++ct) {
                const int row = wc + ct*16 + mm;
                const int ch  = ks*4 + g;
                bfr[ct] = ldsbf(&Bs[cur][row*64 + ((ch ^ (row & 7)) << 3)]);
            }
            __builtin_amdgcn_s_setprio(1);
#pragma unroll
            for (int rt = 0; rt < 4; ++rt)
#pragma unroll
                for (int ct = 0; ct < 4; ++ct)
                    acc[rt][ct] = __builtin_amdgcn_mfma_f32_16x16x32_bf16(
                        af[rt], bfr[ct], acc[rt][ct], 0, 0, 0);
            __builtin_amdgcn_s_setprio(0);
        }

        __builtin_amdgcn_sched_barrier(0);
        __builtin_amdgcn_s_barrier();                 // readers done before restage
        cur = (cur < 2) ? cur + 1 : 0;
    }

    // epilogue (C/D layout: col = lane&15, row = (lane>>4)*4+reg)
    if (VTLAST && z == 2) {
#pragma unroll
        for (int ct = 0; ct < 4; ++ct) {
            const int col = n0 + wc + ct*16 + mm;
            const float bv = Bp[col] * bsc;
#pragma unroll
            for (int rt = 0; rt < 4; ++rt) {
                const int row0 = m0 + wr + rt*16 + g*4;
                const int bb = row0 >> 11, s = row0 & (SQ-1);
                u16x4 pk;
#pragma unroll
                for (int r = 0; r < 4; ++r) pk[r] = f2bf(acc[rt][ct][r] + bv);
                *(u16x4*)&((u16*)Op)[(size_t)(bb*DM + col)*SQ + s] = pk;
            }
        }
    } else {
#pragma unroll
        for (int ct = 0; ct < 4; ++ct) {
            const int col = n0 + wc + ct*16 + mm;
            const float bv = Bp[col] * bsc;
#pragma unroll
            for (int rt = 0; rt < 4; ++rt) {
#pragma unroll
                for (int r = 0; r < 4; ++r) {
                    const int row = m0 + wr + rt*16 + g*4 + r;
                    const float vv = acc[rt][ct][r] + bv;
                    if (OF32) ((float*)Op)[(size_t)row*DM + col] = vv;
                    else      ((u16*) Op)[(size_t)row*DM + col] = f2bf(vv);
                }
            }
        }
    }
}

// ---------------------------------------------------------------------------
// Flash attention, 8 warps x 32 q-rows (256 q/block), KVBLK=64, mfma 32x32x16.
// R6-verified: T14 schedule (SYNC -> issue loads -> compute -> write-late),
// SWZ8 LDS (0 conflicts), z16 C-init, partial lsum, setprio, XCD swizzle.
// ---------------------------------------------------------------------------
__global__ __launch_bounds__(512) void attn_kernel(
    const u16* __restrict__ Q, const u16* __restrict__ K,
    const u16* __restrict__ Vt, u16* __restrict__ Z)
{
    __shared__ __align__(16) u16 Kl[2][64*64];
    __shared__ __align__(16) u16 Vl[2][64*64];

    const int tid  = threadIdx.x;
    const int lane = tid & 63;
    const int wid  = tid >> 6;       // 0..7
    const int c    = lane & 31;
    const int hi   = lane >> 5;
    const int srow = tid >> 3;       // 0..63: one K/V row per thread
    const int c8   = tid & 7;

    // XCD-chunked swizzle over 256 blocks: 32 consecutive wgids per XCD
    const int wg = (blockIdx.x & 7) * 32 + (blockIdx.x >> 3);
    const int qt = wg & 7;
    const int hb = wg >> 3;          // 0..31: 4 (h,b) pairs per XCD
    const int h  = hb & 15;
    const int b  = hb >> 4;
    const int q0 = qt * 256;

    const size_t kbase = (size_t)(b*SQ)*DM + h*HD;
    const size_t vbase = (size_t)((b*16 + h)*HD)*SQ;

    bf16x8 qf[4];
    {
        const size_t qoff = (size_t)(b*SQ + q0 + wid*32 + c)*DM + h*HD + hi*8;
#pragma unroll
        for (int ks = 0; ks < 4; ++ks)
            qf[ks] = ldsbf(&Q[qoff + ks*16]);
    }

    f32x16 oacc[2];
#pragma unroll
    for (int dt = 0; dt < 2; ++dt)
#pragma unroll
        for (int r = 0; r < 16; ++r) oacc[dt][r] = 0.f;
    f32x16 z16;
#pragma unroll
    for (int r = 0; r < 16; ++r) z16[r] = 0.f;
    float lsp[4] = {0.f, 0.f, 0.f, 0.f};

    const int stw = srow*64 + (SWZ8(srow, c8) << 3);
    u16x8 kreg = *(const u16x8*)&K [kbase + (size_t)srow*DM + c8*8];
    u16x8 vreg = *(const u16x8*)&Vt[vbase + (size_t)srow*SQ + c8*8];
    *(u16x8*)&Kl[0][stw] = kreg;
    *(u16x8*)&Vl[0][stw] = vreg;

    for (int t = 0; t < SQ/64; ++t) {
        const int cur = t & 1;
        __syncthreads();             // LDS[cur] staged (writes from prev iter)
        if (t + 1 < SQ/64) {         // issue next loads; latency hides under compute
            kreg = *(const u16x8*)&K [kbase + (size_t)((t+1)*64 + srow)*DM + c8*8];
            vreg = *(const u16x8*)&Vt[vbase + (size_t)srow*SQ + (t+1)*64 + c8*8];
        }

        f32x16 pacc[2];
        __builtin_amdgcn_s_setprio(1);
#pragma unroll
        for (int kt = 0; kt < 2; ++kt) {          // ks = 0, C = z16 (no movs)
            const int row = kt*32 + c;
            bf16x8 kf = ldsbf(&Kl[cur][row*64 + (SWZ8(row, hi) << 3)]);
            pacc[kt] = __builtin_amdgcn_mfma_f32_32x32x16_bf16(kf, qf[0], z16, 0, 0, 0);
        }
#pragma unroll
        for (int ks = 1; ks < 4; ++ks) {
#pragma unroll
            for (int kt = 0; kt < 2; ++kt) {
                const int row = kt*32 + c;
                const int ch  = ks*2 + hi;
                bf16x8 kf = ldsbf(&Kl[cur][row*64 + (SWZ8(row, ch) << 3)]);
                pacc[kt] = __builtin_amdgcn_mfma_f32_32x32x16_bf16(kf, qf[ks], pacc[kt], 0, 0, 0);
            }
        }
        __builtin_amdgcn_s_setprio(0);

#pragma unroll
        for (int kt = 0; kt < 2; ++kt)
#pragma unroll
            for (int r = 0; r < 16; ++r) {
                const float e = __builtin_amdgcn_exp2f(pacc[kt][r]);
                pacc[kt][r] = e;
                lsp[r & 3] += e;
            }

        bf16x8 pa[4];
#pragma unroll
        for (int kt = 0; kt < 2; ++kt)
#pragma unroll
            for (int k2 = 0; k2 < 2; ++k2) {
                const int bs = k2*8;
                unsigned u = cvtpk(pacc[kt][bs+0], pacc[kt][bs+1]);
                unsigned v = cvtpk(pacc[kt][bs+2], pacc[kt][bs+3]);
                unsigned w = cvtpk(pacc[kt][bs+4], pacc[kt][bs+5]);
                unsigned x = cvtpk(pacc[kt][bs+6], pacc[kt][bs+7]);
                swap32(u, w);
                swap32(v, x);
                uint4v fr = {u, v, w, x};
                pa[kt*2 + k2] = __builtin_bit_cast(bf16x8, fr);
            }

        __builtin_amdgcn_s_setprio(1);
#pragma unroll
        for (int kp = 0; kp < 4; ++kp) {
#pragma unroll
            for (int dt = 0; dt < 2; ++dt) {
                const int d  = dt*32 + c;
                const int ch = kp*2 + hi;
                bf16x8 vf = ldsbf(&Vl[cur][d*64 + (SWZ8(d, ch) << 3)]);
                oacc[dt] = __builtin_amdgcn_mfma_f32_32x32x16_bf16(pa[kp], vf, oacc[dt], 0, 0, 0);
            }
        }
        __builtin_amdgcn_s_setprio(0);

        if (t + 1 < SQ/64) {         // write-late: vmcnt wait lands here
            *(u16x8*)&Kl[cur^1][stw] = kreg;
            *(u16x8*)&Vl[cur^1][stw] = vreg;
        }
    }

    float lsum = (lsp[0] + lsp[1]) + (lsp[2] + lsp[3]);
    lsum += __shfl_xor(lsum, 32, 64);
    const float linv = 1.f / lsum;
    float linvr[16];
#pragma unroll
    for (int r = 0; r < 16; ++r)
        linvr[r] = __shfl(linv, (r & 3) + 8*(r >> 2) + 4*hi, 64);

#pragma unroll
    for (int dt = 0; dt < 2; ++dt)
#pragma unroll
        for (int r = 0; r < 16; ++r) {
            const int qrl = (r & 3) + 8*(r >> 2) + 4*hi;
            const size_t row = (size_t)(b*SQ + q0 + wid*32 + qrl);
            Z[row*DM + h*HD + dt*32 + c] = f2bf(oacc[dt][r] * linvr[r]);
        }
}

// ---------------------------------------------------------------------------
extern "C" void kernel_launch(void* const* d_in, const int* in_sizes, int n_in,
                              void* d_out, int out_size, void* d_ws, size_t ws_size,
                              hipStream_t stream)
{
    const float* q  = (const float*)d_in[0];
    const float* k  = (const float*)d_in[1];
    const float* v  = (const float*)d_in[2];
    const float* wq = (const float*)d_in[3];
    const float* bq = (const float*)d_in[4];
    const float* wk = (const float*)d_in[5];
    const float* bk = (const float*)d_in[6];
    const float* wv = (const float*)d_in[7];
    const float* bv = (const float*)d_in[8];
    const float* wo = (const float*)d_in[9];
    const float* bo = (const float*)d_in[10];
    float* out = (float*)d_out;

    char* ws = (char*)d_ws;
    u16* Qc  = (u16*)(ws);                       // bf16 activations, 8 MiB each
    u16* Kc  = (u16*)(ws + 8388608);
    u16* Vc  = (u16*)(ws + 16777216);
    u16* Qb  = (u16*)(ws + 25165824);            // projected Q/K, 8 MiB each
    u16* Kb  = (u16*)(ws + 33554432);
    u16* VtB = (u16*)(ws + 41943040);            // V transposed per head
    u16* WtQ = (u16*)(ws + 50331648);            // 2 MiB each
    u16* WtK = (u16*)(ws + 52428800);
    u16* WtV = (u16*)(ws + 54525952);
    u16* WtO = (u16*)(ws + 56623104);            // end: 56 MiB
    u16* Zb  = Qc;                               // alias: Qc dead after QKV gemm

    wtrans_kernel<<<dim3(32, 32, 4), 256, 0, stream>>>(
        wq, wk, wv, wo, WtQ, WtK, WtV, WtO);

    convert_kernel<<<dim3(3*2048), 256, 0, stream>>>(q, k, v, Qc, Kc, Vc);

    gemm_kernel<false, true><<<dim3(768), 256, 0, stream>>>(
        Qc, Kc, Vc, WtQ, WtK, WtV, bq, bk, bv,
        (void*)Qb, (void*)Kb, (void*)VtB, QSCALE);

    attn_kernel<<<dim3(256), 512, 0, stream>>>(Qb, Kb, VtB, Zb);

    gemm_kernel<true, false><<<dim3(256), 256, 0, stream>>>(
        Zb, Zb, Zb, WtO, WtO, WtO, bo, bo, bo,
        (void*)out, (void*)out, (void*)out, 1.0f);
}

// Round 12
// 116.188 us; speedup vs baseline: 1.1427x; 1.1427x over previous
//
#include <hip/hip_runtime.h>

typedef unsigned short u16;
typedef __bf16 bf16x8 __attribute__((ext_vector_type(8)));
typedef float    f32x4 __attribute__((ext_vector_type(4)));
typedef float   f32x16 __attribute__((ext_vector_type(16)));
typedef u16      u16x8 __attribute__((ext_vector_type(8)));
typedef u16      u16x4 __attribute__((ext_vector_type(4)));
typedef unsigned uint4v __attribute__((ext_vector_type(4)));

#define DM 1024
#define SQ 2048
#define HD 64
#define QSCALE 0.18033688f   /* (1/sqrt(64)) * log2(e), folded into Wq/bq */

// attn LDS bank swizzle (64-col rows) — zero-conflict (verified R4+)
#define SWZ8(row, ch) ((((ch) ^ ((row) & 7) ^ ((row) >> 3)) & 7))

__device__ __forceinline__ u16 f2bf(float f) {
    unsigned u = __builtin_bit_cast(unsigned, f);
    u += 0x7FFFu + ((u >> 16) & 1u);   // RTNE
    return (u16)(u >> 16);
}

__device__ __forceinline__ bf16x8 ldsbf(const u16* p) {
    return __builtin_bit_cast(bf16x8, *(const u16x8*)p);
}

__device__ __forceinline__ unsigned cvtpk(float a, float b) {
    unsigned r;
    asm("v_cvt_pk_bf16_f32 %0, %1, %2" : "=v"(r) : "v"(a), "v"(b));
    return r;
}

__device__ __forceinline__ void swap32(unsigned &a, unsigned &b) {
    asm volatile("v_permlane32_swap_b32 %0, %1" : "+v"(a), "+v"(b));
}

typedef __attribute__((address_space(3))) unsigned lds_u32_t;
typedef __attribute__((address_space(1))) const unsigned glob_u32_t;
__device__ __forceinline__ void gl_lds16(const u16* g, u16* l) {
    __builtin_amdgcn_global_load_lds((glob_u32_t*)g, (lds_u32_t*)l, 16, 0, 0);
}

// ---------------------------------------------------------------------------
// prep: fp32->bf16 convert of q,k,v (blocks 0..6143) + weight transpose
// (blocks 6144..10239).  Wq pre-scaled by QSCALE.
// ---------------------------------------------------------------------------
__global__ __launch_bounds__(256) void prep_kernel(
    const float* __restrict__ q, const float* __restrict__ k,
    const float* __restrict__ v,
    const float* __restrict__ w0, const float* __restrict__ w1,
    const float* __restrict__ w2, const float* __restrict__ w3,
    u16* __restrict__ Qc, u16* __restrict__ Kc, u16* __restrict__ Vc,
    u16* __restrict__ t0, u16* __restrict__ t1,
    u16* __restrict__ t2, u16* __restrict__ t3)
{
    __shared__ float tile[32][33];
    const int bid = blockIdx.x;
    if (bid < 6144) {
        // convert: 2048 blocks per tensor
        const int which = bid >> 11;
        const float* src = (which==0) ? q : (which==1) ? k : v;
        u16* dst         = (which==0) ? Qc : (which==1) ? Kc : Vc;
        const int off = ((bid & 2047) << 11) + threadIdx.x * 8;
        f32x4 x0 = *(const f32x4*)&src[off];
        f32x4 x1 = *(const f32x4*)&src[off + 4];
        u16x8 u;
#pragma unroll
        for (int e = 0; e < 4; ++e) { u[e] = f2bf(x0[e]); u[e+4] = f2bf(x1[e]); }
        *(u16x8*)&dst[off] = u;
    } else {
        // wtrans: W[k][n] (f32) -> Wt[n][k] (bf16); 1024 blocks per weight
        const int t   = bid - 6144;
        const int z   = t >> 10;
        const int rem = t & 1023;
        const float* W = (z==0) ? w0 : (z==1) ? w1 : (z==2) ? w2 : w3;
        u16* T        = (z==0) ? t0 : (z==1) ? t1 : (z==2) ? t2 : t3;
        const float sc = (z==0) ? QSCALE : 1.0f;
        const int tx = threadIdx.x & 31, ty = threadIdx.x >> 5;
        const int n0 = (rem & 31) * 32, k0 = (rem >> 5) * 32;
#pragma unroll
        for (int i = 0; i < 4; ++i)
            tile[ty + 8*i][tx] = W[(size_t)(k0 + ty + 8*i)*DM + n0 + tx];
        __syncthreads();
#pragma unroll
        for (int i = 0; i < 4; ++i)
            T[(size_t)(n0 + ty + 8*i)*DM + k0 + tx] = f2bf(tile[tx][ty + 8*i] * sc);
    }
}

// ---------------------------------------------------------------------------
// GEMM  C[4096][1024] = A[4096][1024](bf16) @ W + bias,  W as Wt[n][k] bf16.
// 128x128 tile, BK=64, 2-buf T3-minimum counted-vmcnt schedule (64 KB LDS,
// 2 blocks/CU):  stage(t+1) -> vmcnt(8) (t+1 floats through compute) ->
// barrier -> 16 ds_read + 32 MFMA -> barrier.  16 fat K-steps.
// Staging via global_load_lds w=16, pre-swizzled source ch^(row&7) (R3: 0-cf).
// XCD-chunked 1-D grid.  bscale0 applied to bias when z==0 (QSCALE folding).
// VTLAST: z==2 output stored transposed per head: Vt[(b*16+h)*64+d][s]
// ---------------------------------------------------------------------------
template<bool OF32, bool VTLAST>
__global__ __launch_bounds__(256) void gemm_kernel(
    const u16* __restrict__ a0, const u16* __restrict__ a1, const u16* __restrict__ a2,
    const u16* __restrict__ w0, const u16* __restrict__ w1, const u16* __restrict__ w2,
    const float* __restrict__ bi0, const float* __restrict__ bi1, const float* __restrict__ bi2,
    void* __restrict__ o0, void* __restrict__ o1, void* __restrict__ o2,
    float bscale0)
{
    __shared__ __align__(16) u16 As[2][128*64];
    __shared__ __align__(16) u16 Bs[2][128*64];

    const int cpx  = gridDim.x >> 3;
    const int wgid = (blockIdx.x & 7) * cpx + (blockIdx.x >> 3);
    const int z   = wgid >> 8;
    const int rem = wgid & 255;
    const int by  = rem >> 3, bx = rem & 7;

    const u16*  Ap  = (z==0) ? a0 : (z==1) ? a1 : a2;
    const u16*  Wp  = (z==0) ? w0 : (z==1) ? w1 : w2;
    const float* Bp = (z==0) ? bi0 : (z==1) ? bi1 : bi2;
    void* Op        = (z==0) ? o0 : (z==1) ? o1 : o2;
    const float bsc = (z==0) ? bscale0 : 1.0f;

    const int tid  = threadIdx.x;
    const int lane = tid & 63;
    const int wv   = tid >> 6;
    const int m0 = by * 128;
    const int n0 = bx * 128;
    const int wr = (wv >> 1) * 64;
    const int wc = (wv & 1) * 64;
    const int g  = lane >> 4;
    const int mm = lane & 15;

    const int l8 = lane >> 3;                 // 0..7: row within 8-row stripe
    const int c8 = lane & 7;                  // chunk lane

    f32x4 acc[4][4];
#pragma unroll
    for (int i = 0; i < 4; ++i)
#pragma unroll
        for (int j = 0; j < 4; ++j) acc[i][j] = f32x4{0.f,0.f,0.f,0.f};

    // stage a 128x64 tile: 4 issues x (4 waves x 8 rows), 8 gl_lds/wave total
    auto stageA = [&](int kt, int buf) {
#pragma unroll
        for (int i = 0; i < 4; ++i) {
            const int row = i*32 + wv*8 + l8;
            const int ch  = c8 ^ (row & 7);   // pre-swizzled source chunk
            gl_lds16(&Ap[(size_t)(m0+row)*DM + kt*64 + ch*8],
                     &As[buf][(i*32 + wv*8)*64]);
        }
    };
    auto stageW = [&](int kt, int buf) {
#pragma unroll
        for (int i = 0; i < 4; ++i) {
            const int row = i*32 + wv*8 + l8;
            const int ch  = c8 ^ (row & 7);
            gl_lds16(&Wp[(size_t)(n0+row)*DM + kt*64 + ch*8],
                     &Bs[buf][(i*32 + wv*8)*64]);
        }
    };

    // prologue: tile 0 in flight
    stageA(0, 0); stageW(0, 0);

    for (int kt = 0; kt < 16; ++kt) {
        const int cur = kt & 1;
        if (kt < 15) { stageA(kt + 1, cur ^ 1); stageW(kt + 1, cur ^ 1); }
        // wait for stage(kt) only; stage(kt+1)'s 8 loads float through compute
        if (kt < 15) asm volatile("s_waitcnt vmcnt(8)" ::: "memory");
        else         asm volatile("s_waitcnt vmcnt(0)" ::: "memory");
        __builtin_amdgcn_s_barrier();                 // stage(kt) visible
        __builtin_amdgcn_sched_barrier(0);

#pragma unroll
        for (int ks = 0; ks < 2; ++ks) {
            bf16x8 af[4], bfr[4];
#pragma unroll
            for (int rt = 0; rt < 4; ++rt) {
                const int row = wr + rt*16 + mm;
                const int ch  = ks*4 + g;
                af[rt] = ldsbf(&As[cur][row*64 + ((ch ^ (row & 7)) << 3)]);
            }
#pragma unroll
            for (int ct = 0; ct < 4; ++ct) {
                const int row = wc + ct*16 + mm;
                const int ch  = ks*4 + g;
                bfr[ct] = ldsbf(&Bs[cur][row*64 + ((ch ^ (row & 7)) << 3)]);
            }
            __builtin_amdgcn_s_setprio(1);
#pragma unroll
            for (int rt = 0; rt < 4; ++rt)
#pragma unroll
                for (int ct = 0; ct < 4; ++ct)
                    acc[rt][ct] = __builtin_amdgcn_mfma_f32_16x16x32_bf16(
                        af[rt], bfr[ct], acc[rt][ct], 0, 0, 0);
            __builtin_amdgcn_s_setprio(0);
        }

        __builtin_amdgcn_sched_barrier(0);
        __builtin_amdgcn_s_barrier();                 // readers done before restage
    }

    // epilogue (C/D layout: col = lane&15, row = (lane>>4)*4+reg)
    if (VTLAST && z == 2) {
#pragma unroll
        for (int ct = 0; ct < 4; ++ct) {
            const int col = n0 + wc + ct*16 + mm;
            const float bv = Bp[col] * bsc;
#pragma unroll
            for (int rt = 0; rt < 4; ++rt) {
                const int row0 = m0 + wr + rt*16 + g*4;
                const int bb = row0 >> 11, s = row0 & (SQ-1);
                u16x4 pk;
#pragma unroll
                for (int r = 0; r < 4; ++r) pk[r] = f2bf(acc[rt][ct][r] + bv);
                *(u16x4*)&((u16*)Op)[(size_t)(bb*DM + col)*SQ + s] = pk;
            }
        }
    } else {
#pragma unroll
        for (int ct = 0; ct < 4; ++ct) {
            const int col = n0 + wc + ct*16 + mm;
            const float bv = Bp[col] * bsc;
#pragma unroll
            for (int rt = 0; rt < 4; ++rt) {
#pragma unroll
                for (int r = 0; r < 4; ++r) {
                    const int row = m0 + wr + rt*16 + g*4 + r;
                    const float vv = acc[rt][ct][r] + bv;
                    if (OF32) ((float*)Op)[(size_t)row*DM + col] = vv;
                    else      ((u16*) Op)[(size_t)row*DM + col] = f2bf(vv);
                }
            }
        }
    }
}

// ---------------------------------------------------------------------------
// Flash attention, 8 warps x 32 q-rows (256 q/block), KVBLK=64, mfma 32x32x16.
// R6-verified: T14 schedule (SYNC -> issue loads -> compute -> write-late),
// SWZ8 LDS (0 conflicts), z16 C-init, partial lsum, setprio, XCD swizzle.
// ---------------------------------------------------------------------------
__global__ __launch_bounds__(512) void attn_kernel(
    const u16* __restrict__ Q, const u16* __restrict__ K,
    const u16* __restrict__ Vt, u16* __restrict__ Z)
{
    __shared__ __align__(16) u16 Kl[2][64*64];
    __shared__ __align__(16) u16 Vl[2][64*64];

    const int tid  = threadIdx.x;
    const int lane = tid & 63;
    const int wid  = tid >> 6;       // 0..7
    const int c    = lane & 31;
    const int hi   = lane >> 5;
    const int srow = tid >> 3;       // 0..63: one K/V row per thread
    const int c8   = tid & 7;

    // XCD-chunked swizzle over 256 blocks: 32 consecutive wgids per XCD
    const int wg = (blockIdx.x & 7) * 32 + (blockIdx.x >> 3);
    const int qt = wg & 7;
    const int hb = wg >> 3;          // 0..31: 4 (h,b) pairs per XCD
    const int h  = hb & 15;
    const int b  = hb >> 4;
    const int q0 = qt * 256;

    const size_t kbase = (size_t)(b*SQ)*DM + h*HD;
    const size_t vbase = (size_t)((b*16 + h)*HD)*SQ;

    bf16x8 qf[4];
    {
        const size_t qoff = (size_t)(b*SQ + q0 + wid*32 + c)*DM + h*HD + hi*8;
#pragma unroll
        for (int ks = 0; ks < 4; ++ks)
            qf[ks] = ldsbf(&Q[qoff + ks*16]);
    }

    f32x16 oacc[2];
#pragma unroll
    for (int dt = 0; dt < 2; ++dt)
#pragma unroll
        for (int r = 0; r < 16; ++r) oacc[dt][r] = 0.f;
    f32x16 z16;
#pragma unroll
    for (int r = 0; r < 16; ++r) z16[r] = 0.f;
    float lsp[4] = {0.f, 0.f, 0.f, 0.f};

    const int stw = srow*64 + (SWZ8(srow, c8) << 3);
    u16x8 kreg = *(const u16x8*)&K [kbase + (size_t)srow*DM + c8*8];
    u16x8 vreg = *(const u16x8*)&Vt[vbase + (size_t)srow*SQ + c8*8];
    *(u16x8*)&Kl[0][stw] = kreg;
    *(u16x8*)&Vl[0][stw] = vreg;

    for (int t = 0; t < SQ/64; ++t) {
        const int cur = t & 1;
        __syncthreads();             // LDS[cur] staged (writes from prev iter)
        if (t + 1 < SQ/64) {         // issue next loads; latency hides under compute
            kreg = *(const u16x8*)&K [kbase + (size_t)((t+1)*64 + srow)*DM + c8*8];
            vreg = *(const u16x8*)&Vt[vbase + (size_t)srow*SQ + (t+1)*64 + c8*8];
        }

        f32x16 pacc[2];
        __builtin_amdgcn_s_setprio(1);
#pragma unroll
        for (int kt = 0; kt < 2; ++kt) {          // ks = 0, C = z16 (no movs)
            const int row = kt*32 + c;
            bf16x8 kf = ldsbf(&Kl[cur][row*64 + (SWZ8(row, hi) << 3)]);
            pacc[kt] = __builtin_amdgcn_mfma_f32_32x32x16_bf16(kf, qf[0], z16, 0, 0, 0);
        }
#pragma unroll
        for (int ks = 1; ks < 4; ++ks) {
#pragma unroll
            for (int kt = 0; kt < 2; ++kt) {
                const int row = kt*32 + c;
                const int ch  = ks*2 + hi;
                bf16x8 kf = ldsbf(&Kl[cur][row*64 + (SWZ8(row, ch) << 3)]);
                pacc[kt] = __builtin_amdgcn_mfma_f32_32x32x16_bf16(kf, qf[ks], pacc[kt], 0, 0, 0);
            }
        }
        __builtin_amdgcn_s_setprio(0);

#pragma unroll
        for (int kt = 0; kt < 2; ++kt)
#pragma unroll
            for (int r = 0; r < 16; ++r) {
                const float e = __builtin_amdgcn_exp2f(pacc[kt][r]);
                pacc[kt][r] = e;
                lsp[r & 3] += e;
            }

        bf16x8 pa[4];
#pragma unroll
        for (int kt = 0; kt < 2; ++kt)
#pragma unroll
            for (int k2 = 0; k2 < 2; ++k2) {
                const int bs = k2*8;
                unsigned u = cvtpk(pacc[kt][bs+0], pacc[kt][bs+1]);
                unsigned v = cvtpk(pacc[kt][bs+2], pacc[kt][bs+3]);
                unsigned w = cvtpk(pacc[kt][bs+4], pacc[kt][bs+5]);
                unsigned x = cvtpk(pacc[kt][bs+6], pacc[kt][bs+7]);
                swap32(u, w);
                swap32(v, x);
                uint4v fr = {u, v, w, x};
                pa[kt*2 + k2] = __builtin_bit_cast(bf16x8, fr);
            }

        __builtin_amdgcn_s_setprio(1);
#pragma unroll
        for (int kp = 0; kp < 4; ++kp) {
#pragma unroll
            for (int dt = 0; dt < 2; ++dt) {
                const int d  = dt*32 + c;
                const int ch = kp*2 + hi;
                bf16x8 vf = ldsbf(&Vl[cur][d*64 + (SWZ8(d, ch) << 3)]);
                oacc[dt] = __builtin_amdgcn_mfma_f32_32x32x16_bf16(pa[kp], vf, oacc[dt], 0, 0, 0);
            }
        }
        __builtin_amdgcn_s_setprio(0);

        if (t + 1 < SQ/64) {         // write-late: vmcnt wait lands here
            *(u16x8*)&Kl[cur^1][stw] = kreg;
            *(u16x8*)&Vl[cur^1][stw] = vreg;
        }
    }

    float lsum = (lsp[0] + lsp[1]) + (lsp[2] + lsp[3]);
    lsum += __shfl_xor(lsum, 32, 64);
    const float linv = 1.f / lsum;
    float linvr[16];
#pragma unroll
    for (int r = 0; r < 16; ++r)
        linvr[r] = __shfl(linv, (r & 3) + 8*(r >> 2) + 4*hi, 64);

#pragma unroll
    for (int dt = 0; dt < 2; ++dt)
#pragma unroll
        for (int r = 0; r < 16; ++r) {
            const int qrl = (r & 3) + 8*(r >> 2) + 4*hi;
            const size_t row = (size_t)(b*SQ + q0 + wid*32 + qrl);
            Z[row*DM + h*HD + dt*32 + c] = f2bf(oacc[dt][r] * linvr[r]);
        }
}

// ---------------------------------------------------------------------------
extern "C" void kernel_launch(void* const* d_in, const int* in_sizes, int n_in,
                              void* d_out, int out_size, void* d_ws, size_t ws_size,
                              hipStream_t stream)
{
    const float* q  = (const float*)d_in[0];
    const float* k  = (const float*)d_in[1];
    const float* v  = (const float*)d_in[2];
    const float* wq = (const float*)d_in[3];
    const float* bq = (const float*)d_in[4];
    const float* wk = (const float*)d_in[5];
    const float* bk = (const float*)d_in[6];
    const float* wv = (const float*)d_in[7];
    const float* bv = (const float*)d_in[8];
    const float* wo = (const float*)d_in[9];
    const float* bo = (const float*)d_in[10];
    float* out = (float*)d_out;

    char* ws = (char*)d_ws;
    u16* Qc  = (u16*)(ws);                       // bf16 activations, 8 MiB each
    u16* Kc  = (u16*)(ws + 8388608);
    u16* Vc  = (u16*)(ws + 16777216);
    u16* Qb  = (u16*)(ws + 25165824);            // projected Q/K, 8 MiB each
    u16* Kb  = (u16*)(ws + 33554432);
    u16* VtB = (u16*)(ws + 41943040);            // V transposed per head
    u16* WtQ = (u16*)(ws + 50331648);            // 2 MiB each
    u16* WtK = (u16*)(ws + 52428800);
    u16* WtV = (u16*)(ws + 54525952);
    u16* WtO = (u16*)(ws + 56623104);            // end: 56 MiB
    u16* Zb  = Qc;                               // alias: Qc dead after QKV gemm

    // merged convert + weight-transpose (one launch)
    prep_kernel<<<dim3(6144 + 4096), 256, 0, stream>>>(
        q, k, v, wq, wk, wv, wo, Qc, Kc, Vc, WtQ, WtK, WtV, WtO);

    gemm_kernel<false, true><<<dim3(768), 256, 0, stream>>>(
        Qc, Kc, Vc, WtQ, WtK, WtV, bq, bk, bv,
        (void*)Qb, (void*)Kb, (void*)VtB, QSCALE);

    attn_kernel<<<dim3(256), 512, 0, stream>>>(Qb, Kb, VtB, Zb);

    gemm_kernel<true, false><<<dim3(256), 256, 0, stream>>>(
        Zb, Zb, Zb, WtO, WtO, WtO, bo, bo, bo,
        (void*)out, (void*)out, (void*)out, 1.0f);
}